// Round 1
// baseline (43.587 us; speedup 1.0000x reference)
//
#include <hip/hip_runtime.h>

#define TOKS 8192   // B*S
#define NB 16
#define NS 512

// ---- workspace layout (floats) ----
#define WS_Q   0            // [2][8192]
#define WS_K   16384        // [2][8192]
#define WS_V   32768        // [2][8192][4]
#define WS_HO  98304        // [8192][8]
#define WS_CF  163840       // 264 coefficient floats

// ======================= n=4 statevector (per-thread, 16 amps) =======================

template<int W>
__device__ __forceinline__ void rx4(float* re, float* im, float c, float s) {
    constexpr int mask = 1 << W;
    #pragma unroll
    for (int a = 0; a < 16; ++a) {
        if (a & mask) continue;
        constexpr int dummy = 0; (void)dummy;
        int b = a | mask;
        float ra = re[a], ia = im[a], rb = re[b], ib = im[b];
        re[a] = c*ra + s*ib;
        im[a] = c*ia - s*rb;
        re[b] = c*rb + s*ia;
        im[b] = c*ib - s*ra;
    }
}

template<int C, int T>
__device__ __forceinline__ void cnot4(float* re, float* im) {
    constexpr int cm = 1 << C, tm = 1 << T;
    #pragma unroll
    for (int a = 0; a < 16; ++a) {
        if (!(a & cm) || (a & tm)) continue;
        int b = a | tm;
        float r = re[a]; re[a] = re[b]; re[b] = r;
        float i = im[a]; im[a] = im[b]; im[b] = i;
    }
}

// cf = {ur,ui,vr,vi,vpr,vpi,upr,upi}
template<int W>
__device__ __forceinline__ void rot4(float* re, float* im, const float* __restrict__ cf) {
    float ur=cf[0], ui=cf[1], vr=cf[2], vi=cf[3], vpr=cf[4], vpi=cf[5], upr=cf[6], upi=cf[7];
    constexpr int mask = 1 << W;
    #pragma unroll
    for (int a = 0; a < 16; ++a) {
        if (a & mask) continue;
        int b = a | mask;
        float ra=re[a], ia=im[a], rb=re[b], ib=im[b];
        re[a] = ur*ra - ui*ia + vr*rb - vi*ib;
        im[a] = ur*ia + ui*ra + vr*ib + vi*rb;
        re[b] = vpr*ra - vpi*ia + upr*rb - upi*ib;
        im[b] = vpr*ia + vpi*ra + upr*ib + upi*rb;
    }
}

__device__ __forceinline__ float4 zexp4_all(const float* re, const float* im) {
    float4 e = {0.f, 0.f, 0.f, 0.f};
    #pragma unroll
    for (int a = 0; a < 16; ++a) {
        float p = re[a]*re[a] + im[a]*im[a];
        e.x += (a & 1) ? -p : p;
        e.y += (a & 2) ? -p : p;
        e.z += (a & 4) ? -p : p;
        e.w += (a & 8) ? -p : p;
    }
    return e;
}

__device__ __forceinline__ float zexp0(const float* re, const float* im) {
    float e = 0.f;
    #pragma unroll
    for (int a = 0; a < 16; ++a) {
        float p = re[a]*re[a] + im[a]*im[a];
        e += (a & 1) ? -p : p;
    }
    return e;
}

// ======================= kernel 0: gate-coefficient precompute =======================
// coef sets 0..23: [h][circ V/Q/K][wire] Rot coefs (8 floats each)
// sets 24..31: merge Rot coefs
// coef[256..263]: extra RX (c,s) for Q(h0),Q(h1),K(h0),K(h1)
__global__ __launch_bounds__(64)
void k_prep(const float* __restrict__ Vw, const float* __restrict__ Qw,
            const float* __restrict__ Kw, const float* __restrict__ Mw,
            float* __restrict__ coef)
{
    int tid = threadIdx.x;
    if (tid < 32) {
        float phi, th, om;
        if (tid < 24) {
            int h = tid / 12, cc = (tid % 12) / 4, w = tid % 4;
            const float* wp;
            if (cc == 0)      wp = Vw + h*12 + 3*w;
            else if (cc == 1) wp = Qw + h*13 + 3*w;
            else              wp = Kw + h*13 + 3*w;
            phi = wp[0]; th = wp[1]; om = wp[2];
        } else {
            int w = tid - 24;
            phi = Mw[3*w]; th = Mw[3*w+1]; om = Mw[3*w+2];
        }
        float st, ct, s1, c1, s2, c2;
        __sincosf(0.5f*th, &st, &ct);
        __sincosf(0.5f*(om+phi), &s1, &c1);
        __sincosf(0.5f*(om-phi), &s2, &c2);
        float* o = coef + tid*8;
        o[0] = c1*ct;  o[1] = -s1*ct;   // u  = ep*c,        ep = c1 - i s1
        o[2] = -c2*st; o[3] = s2*st;    // v  = -conj(em)*s, em = c2 + i s2
        o[4] = c2*st;  o[5] = s2*st;    // vp = em*s
        o[6] = c1*ct;  o[7] = s1*ct;    // up = conj(ep)*c
    } else if (tid < 36) {
        int k = tid - 32;               // 0,1: Q h0/h1 ; 2,3: K h0/h1
        int h = k & 1;
        float th = (k < 2 ? Qw : Kw)[h*13 + 12];
        float s, c; __sincosf(0.5f*th, &s, &c);
        coef[256 + k*2]     = c;
        coef[256 + k*2 + 1] = s;
    }
}

// ======================= kernel 1: LN + head circuits (thread per token) =======================
__global__ __launch_bounds__(64)
void k_heads(const float* __restrict__ x, const float* __restrict__ coef,
             float* __restrict__ Qo, float* __restrict__ Ko, float* __restrict__ Vo)
{
    int t = blockIdx.x * 64 + threadIdx.x;

    const float4* xp = (const float4*)(x + t*8);
    float4 xa = xp[0], xb = xp[1];
    float xv[8] = {xa.x, xa.y, xa.z, xa.w, xb.x, xb.y, xb.z, xb.w};
    float m = 0.f;
    #pragma unroll
    for (int e = 0; e < 8; ++e) m += xv[e];
    m *= 0.125f;
    float var = 0.f;
    #pragma unroll
    for (int e = 0; e < 8; ++e) { float d = xv[e]-m; var += d*d; }
    float inv = rsqrtf(var*0.125f + 1e-5f);

    #pragma unroll
    for (int h = 0; h < 2; ++h) {
        // ---- shared prefix: angle encoding + CNOT ring ----
        float er[16], ei[16];
        #pragma unroll
        for (int a = 0; a < 16; ++a) { er[a] = 0.f; ei[a] = 0.f; }
        er[0] = 1.f;
        float s, c;
        __sincosf(0.5f*((xv[h*4+0]-m)*inv), &s, &c); rx4<0>(er, ei, c, s);
        __sincosf(0.5f*((xv[h*4+1]-m)*inv), &s, &c); rx4<1>(er, ei, c, s);
        __sincosf(0.5f*((xv[h*4+2]-m)*inv), &s, &c); rx4<2>(er, ei, c, s);
        __sincosf(0.5f*((xv[h*4+3]-m)*inv), &s, &c); rx4<3>(er, ei, c, s);
        cnot4<0,1>(er, ei); cnot4<1,2>(er, ei); cnot4<2,3>(er, ei); cnot4<3,0>(er, ei);

        float sr[16], sm[16];
        // ---- V circuit ----
        #pragma unroll
        for (int a = 0; a < 16; ++a) { sr[a] = er[a]; sm[a] = ei[a]; }
        rot4<0>(sr, sm, coef + (h*12 + 0)*8);
        rot4<1>(sr, sm, coef + (h*12 + 1)*8);
        rot4<2>(sr, sm, coef + (h*12 + 2)*8);
        rot4<3>(sr, sm, coef + (h*12 + 3)*8);
        ((float4*)Vo)[h*TOKS + t] = zexp4_all(sr, sm);

        // ---- Q circuit ----
        #pragma unroll
        for (int a = 0; a < 16; ++a) { sr[a] = er[a]; sm[a] = ei[a]; }
        rot4<0>(sr, sm, coef + (h*12 + 4)*8);
        rot4<1>(sr, sm, coef + (h*12 + 5)*8);
        rot4<2>(sr, sm, coef + (h*12 + 6)*8);
        rot4<3>(sr, sm, coef + (h*12 + 7)*8);
        rx4<0>(sr, sm, coef[256 + h*2], coef[256 + h*2 + 1]);
        Qo[h*TOKS + t] = zexp0(sr, sm);

        // ---- K circuit ----
        #pragma unroll
        for (int a = 0; a < 16; ++a) { sr[a] = er[a]; sm[a] = ei[a]; }
        rot4<0>(sr, sm, coef + (h*12 +  8)*8);
        rot4<1>(sr, sm, coef + (h*12 +  9)*8);
        rot4<2>(sr, sm, coef + (h*12 + 10)*8);
        rot4<3>(sr, sm, coef + (h*12 + 11)*8);
        rx4<0>(sr, sm, coef[260 + h*2], coef[260 + h*2 + 1]);
        Ko[h*TOKS + t] = zexp0(sr, sm);
    }
}

// ======================= kernel 2: distance-kernel attention =======================
// grid 1024: blk = h*512 + b*32 + rg ; block 256 threads = 4 waves;
// each 16-lane group owns one output row i. Logits in [-2,0] -> no max needed.
__global__ __launch_bounds__(256)
void k_attn(const float* __restrict__ Qo, const float* __restrict__ Ko,
            const float* __restrict__ Vo, float* __restrict__ HO)
{
    __shared__ float Ks[512];
    __shared__ float4 Vs[512];
    int blk = blockIdx.x;
    int rg = blk & 31, b = (blk >> 5) & 15, h = blk >> 9;
    int base = h*TOKS + b*NS;
    int tid = threadIdx.x;
    #pragma unroll
    for (int k = 0; k < 2; ++k) {
        int j = k*256 + tid;
        Ks[j] = Ko[base + j];
        Vs[j] = ((const float4*)Vo)[base + j];
    }
    __syncthreads();

    int lane = tid & 63;
    int w = tid >> 6;          // wave 0..3
    int g = lane >> 4;         // 16-lane group 0..3
    int l16 = lane & 15;
    int i = rg*16 + w*4 + g;   // output row
    float q = Qo[base + i];

    float sum = 0.f, a0 = 0.f, a1 = 0.f, a2 = 0.f, a3 = 0.f;
    #pragma unroll
    for (int k = 0; k < 32; ++k) {
        int j = k*16 + l16;
        float d = q - Ks[j];
        float p = __expf(-0.5f*d*d);
        float4 vv = Vs[j];
        sum += p; a0 += p*vv.x; a1 += p*vv.y; a2 += p*vv.z; a3 += p*vv.w;
    }
    #pragma unroll
    for (int off = 1; off < 16; off <<= 1) {
        sum += __shfl_xor(sum, off, 16);
        a0  += __shfl_xor(a0,  off, 16);
        a1  += __shfl_xor(a1,  off, 16);
        a2  += __shfl_xor(a2,  off, 16);
        a3  += __shfl_xor(a3,  off, 16);
    }
    if (l16 == 0) {
        float r = 1.0f / sum;
        float4 o = {a0*r, a1*r, a2*r, a3*r};
        *((float4*)(HO + (b*NS + i)*8 + h*4)) = o;
    }
}

// ======================= kernel 3: n=8 merge circuit (wave per token) =======================
// amplitude a = (r<<6) | lane ; wire w <-> bit w of a (lane bits 0..5, reg bits 6..7)

template<int W>
__device__ __forceinline__ void c_rx(float (&sr)[4], float (&si)[4], float c, float s) {
    if constexpr (W <= 5) {
        #pragma unroll
        for (int r = 0; r < 4; ++r) {
            float pr = __shfl_xor(sr[r], 1 << W, 64);
            float pi = __shfl_xor(si[r], 1 << W, 64);
            float nr = c*sr[r] + s*pi;
            float ni = c*si[r] - s*pr;
            sr[r] = nr; si[r] = ni;
        }
    } else if constexpr (W == 6) {   // pairs (0,1),(2,3)
        #pragma unroll
        for (int k = 0; k < 2; ++k) {
            int lo = k*2, hi = lo + 1;
            float rl=sr[lo], il=si[lo], rh=sr[hi], ih=si[hi];
            sr[lo] = c*rl + s*ih; si[lo] = c*il - s*rh;
            sr[hi] = c*rh + s*il; si[hi] = c*ih - s*rl;
        }
    } else {                         // W==7: pairs (0,2),(1,3)
        #pragma unroll
        for (int k = 0; k < 2; ++k) {
            int lo = k, hi = k + 2;
            float rl=sr[lo], il=si[lo], rh=sr[hi], ih=si[hi];
            sr[lo] = c*rl + s*ih; si[lo] = c*il - s*rh;
            sr[hi] = c*rh + s*il; si[hi] = c*ih - s*rl;
        }
    }
}

template<int W>
__device__ __forceinline__ void c_rot(float (&sr)[4], float (&si)[4],
                                      const float* __restrict__ cf, int lane) {
    float ur=cf[0], ui=cf[1], vr=cf[2], vi=cf[3], vpr=cf[4], vpi=cf[5], upr=cf[6], upi=cf[7];
    if constexpr (W <= 5) {
        int bit = (lane >> W) & 1;
        float ar = bit ? upr : ur, ai = bit ? upi : ui;
        float br = bit ? vpr : vr, bi = bit ? vpi : vi;
        #pragma unroll
        for (int r = 0; r < 4; ++r) {
            float pr = __shfl_xor(sr[r], 1 << W, 64);
            float pi = __shfl_xor(si[r], 1 << W, 64);
            float nr = ar*sr[r] - ai*si[r] + br*pr - bi*pi;
            float ni = ar*si[r] + ai*sr[r] + br*pi + bi*pr;
            sr[r] = nr; si[r] = ni;
        }
    } else if constexpr (W == 6) {
        #pragma unroll
        for (int k = 0; k < 2; ++k) {
            int lo = k*2, hi = lo + 1;
            float rl=sr[lo], il=si[lo], rh=sr[hi], ih=si[hi];
            sr[lo] = ur*rl - ui*il + vr*rh - vi*ih;
            si[lo] = ur*il + ui*rl + vr*ih + vi*rh;
            sr[hi] = vpr*rl - vpi*il + upr*rh - upi*ih;
            si[hi] = vpr*il + vpi*rl + upr*ih + upi*rh;
        }
    } else {
        #pragma unroll
        for (int k = 0; k < 2; ++k) {
            int lo = k, hi = k + 2;
            float rl=sr[lo], il=si[lo], rh=sr[hi], ih=si[hi];
            sr[lo] = ur*rl - ui*il + vr*rh - vi*ih;
            si[lo] = ur*il + ui*rl + vr*ih + vi*rh;
            sr[hi] = vpr*rl - vpi*il + upr*rh - upi*ih;
            si[hi] = vpr*il + vpi*rl + upr*ih + upi*rh;
        }
    }
}

template<int C, int T>   // both lane bits, C control, T target
__device__ __forceinline__ void c_cnot_ll(float (&sr)[4], float (&si)[4], int lane) {
    int bc = (lane >> C) & 1;
    #pragma unroll
    for (int r = 0; r < 4; ++r) {
        float pr = __shfl_xor(sr[r], 1 << T, 64);
        float pi = __shfl_xor(si[r], 1 << T, 64);
        sr[r] = bc ? pr : sr[r];
        si[r] = bc ? pi : si[r];
    }
}

__global__ __launch_bounds__(256)
void k_merge(const float* __restrict__ HO, const float* __restrict__ x,
             const float* __restrict__ coef, float* __restrict__ out)
{
    int lane = threadIdx.x & 63;
    int t = blockIdx.x * 4 + (threadIdx.x >> 6);

    const float4* hp = (const float4*)(HO + t*8);
    float4 h0 = hp[0], h1 = hp[1];
    float ang[8] = {h0.x, h0.y, h0.z, h0.w, h1.x, h1.y, h1.z, h1.w};

    float sr[4], si[4];
    #pragma unroll
    for (int r = 0; r < 4; ++r) { sr[r] = 0.f; si[r] = 0.f; }
    sr[0] = (lane == 0) ? 1.f : 0.f;

    float s, c;
    // ---- angle encoding RX(ang[w]) on wire w ----
    __sincosf(0.5f*ang[0], &s, &c); c_rx<0>(sr, si, c, s);
    __sincosf(0.5f*ang[1], &s, &c); c_rx<1>(sr, si, c, s);
    __sincosf(0.5f*ang[2], &s, &c); c_rx<2>(sr, si, c, s);
    __sincosf(0.5f*ang[3], &s, &c); c_rx<3>(sr, si, c, s);
    __sincosf(0.5f*ang[4], &s, &c); c_rx<4>(sr, si, c, s);
    __sincosf(0.5f*ang[5], &s, &c); c_rx<5>(sr, si, c, s);
    __sincosf(0.5f*ang[6], &s, &c); c_rx<6>(sr, si, c, s);
    __sincosf(0.5f*ang[7], &s, &c); c_rx<7>(sr, si, c, s);

    // ---- CNOT ring (0,1)...(6,7),(7,0) ----
    c_cnot_ll<0,1>(sr, si, lane);
    c_cnot_ll<1,2>(sr, si, lane);
    c_cnot_ll<2,3>(sr, si, lane);
    c_cnot_ll<3,4>(sr, si, lane);
    c_cnot_ll<4,5>(sr, si, lane);
    { // (5,6): control lane bit5, target reg bit6: swap reg pairs (0,1),(2,3)
        int b5 = (lane >> 5) & 1;
        float t0=sr[0], t1=sr[1], t2=sr[2], t3=sr[3];
        sr[0] = b5 ? t1 : t0; sr[1] = b5 ? t0 : t1;
        sr[2] = b5 ? t3 : t2; sr[3] = b5 ? t2 : t3;
        float u0=si[0], u1=si[1], u2=si[2], u3=si[3];
        si[0] = b5 ? u1 : u0; si[1] = b5 ? u0 : u1;
        si[2] = b5 ? u3 : u2; si[3] = b5 ? u2 : u3;
    }
    { // (6,7): control reg bit6 (r=1,3), target reg bit7: swap r1<->r3
        float tr = sr[1]; sr[1] = sr[3]; sr[3] = tr;
        float ti = si[1]; si[1] = si[3]; si[3] = ti;
    }
    { // (7,0): control reg bit7 (r=2,3), target lane bit0
        sr[2] = __shfl_xor(sr[2], 1, 64); si[2] = __shfl_xor(si[2], 1, 64);
        sr[3] = __shfl_xor(sr[3], 1, 64); si[3] = __shfl_xor(si[3], 1, 64);
    }

    // ---- trainable Rot layer (precomputed coefs, sets 24..31) ----
    c_rot<0>(sr, si, coef + (24+0)*8, lane);
    c_rot<1>(sr, si, coef + (24+1)*8, lane);
    c_rot<2>(sr, si, coef + (24+2)*8, lane);
    c_rot<3>(sr, si, coef + (24+3)*8, lane);
    c_rot<4>(sr, si, coef + (24+4)*8, lane);
    c_rot<5>(sr, si, coef + (24+5)*8, lane);
    c_rot<6>(sr, si, coef + (24+6)*8, lane);
    c_rot<7>(sr, si, coef + (24+7)*8, lane);

    // ---- Z expectation on all 8 wires ----
    float p0 = sr[0]*sr[0] + si[0]*si[0];
    float p1 = sr[1]*sr[1] + si[1]*si[1];
    float p2 = sr[2]*sr[2] + si[2]*si[2];
    float p3 = sr[3]*sr[3] + si[3]*si[3];
    float P  = p0 + p1 + p2 + p3;
    float e0 = (lane & 1)  ? -P : P;
    float e1 = (lane & 2)  ? -P : P;
    float e2 = (lane & 4)  ? -P : P;
    float e3 = (lane & 8)  ? -P : P;
    float e4 = (lane & 16) ? -P : P;
    float e5 = (lane & 32) ? -P : P;
    float e6 = p0 - p1 + p2 - p3;
    float e7 = p0 + p1 - p2 - p3;
    #pragma unroll
    for (int off = 1; off < 64; off <<= 1) {
        e0 += __shfl_xor(e0, off, 64);
        e1 += __shfl_xor(e1, off, 64);
        e2 += __shfl_xor(e2, off, 64);
        e3 += __shfl_xor(e3, off, 64);
        e4 += __shfl_xor(e4, off, 64);
        e5 += __shfl_xor(e5, off, 64);
        e6 += __shfl_xor(e6, off, 64);
        e7 += __shfl_xor(e7, off, 64);
    }
    if (lane == 0) {
        const float4* xp = (const float4*)(x + t*8);
        float4 x0 = xp[0], x1 = xp[1];
        float4 o0 = {e0 + x0.x, e1 + x0.y, e2 + x0.z, e3 + x0.w};
        float4 o1 = {e4 + x1.x, e5 + x1.y, e6 + x1.z, e7 + x1.w};
        float4* op = (float4*)(out + t*8);
        op[0] = o0; op[1] = o1;
    }
}

// ======================= launch =======================
extern "C" void kernel_launch(void* const* d_in, const int* in_sizes, int n_in,
                              void* d_out, int out_size, void* d_ws, size_t ws_size,
                              hipStream_t stream) {
    (void)in_sizes; (void)n_in; (void)out_size; (void)ws_size;
    const float* x  = (const float*)d_in[0];
    const float* Vw = (const float*)d_in[1];
    const float* Qw = (const float*)d_in[2];
    const float* Kw = (const float*)d_in[3];
    const float* Mw = (const float*)d_in[4];
    float* out = (float*)d_out;
    float* ws  = (float*)d_ws;

    float* Qo   = ws + WS_Q;
    float* Ko   = ws + WS_K;
    float* Vo   = ws + WS_V;
    float* HO   = ws + WS_HO;
    float* coef = ws + WS_CF;

    hipLaunchKernelGGL(k_prep,  dim3(1),    dim3(64),  0, stream, Vw, Qw, Kw, Mw, coef);
    hipLaunchKernelGGL(k_heads, dim3(128),  dim3(64),  0, stream, x, coef, Qo, Ko, Vo);
    hipLaunchKernelGGL(k_attn,  dim3(1024), dim3(256), 0, stream, Qo, Ko, Vo, HO);
    hipLaunchKernelGGL(k_merge, dim3(2048), dim3(256), 0, stream, HO, x, coef, out);
}

// Round 2
// 35.369 us; speedup vs baseline: 1.2324x; 1.2324x over previous
//
#include <hip/hip_runtime.h>

#define TOKS 8192   // B*S
#define NB 16
#define NS 512

// ---- workspace layout (floats) ----
#define WS_Q   0            // [2][8192]
#define WS_K   16384        // [2][8192]
#define WS_V   32768        // [2][8192][4]
#define WS_HO  98304        // [8192][8]
#define WS_CF  163840       // 264 coefficient floats

// ======================= n=4 statevector (per-thread, 16 amps) =======================

template<int W>
__device__ __forceinline__ void rx4(float* re, float* im, float c, float s) {
    constexpr int mask = 1 << W;
    #pragma unroll
    for (int a = 0; a < 16; ++a) {
        if (a & mask) continue;
        int b = a | mask;
        float ra = re[a], ia = im[a], rb = re[b], ib = im[b];
        re[a] = c*ra + s*ib;
        im[a] = c*ia - s*rb;
        re[b] = c*rb + s*ia;
        im[b] = c*ib - s*ra;
    }
}

template<int C, int T>
__device__ __forceinline__ void cnot4(float* re, float* im) {
    constexpr int cm = 1 << C, tm = 1 << T;
    #pragma unroll
    for (int a = 0; a < 16; ++a) {
        if (!(a & cm) || (a & tm)) continue;
        int b = a | tm;
        float r = re[a]; re[a] = re[b]; re[b] = r;
        float i = im[a]; im[a] = im[b]; im[b] = i;
    }
}

// cf = {ur,ui,vr,vi,vpr,vpi,upr,upi}
template<int W>
__device__ __forceinline__ void rot4(float* re, float* im, const float* __restrict__ cf) {
    float ur=cf[0], ui=cf[1], vr=cf[2], vi=cf[3], vpr=cf[4], vpi=cf[5], upr=cf[6], upi=cf[7];
    constexpr int mask = 1 << W;
    #pragma unroll
    for (int a = 0; a < 16; ++a) {
        if (a & mask) continue;
        int b = a | mask;
        float ra=re[a], ia=im[a], rb=re[b], ib=im[b];
        re[a] = ur*ra - ui*ia + vr*rb - vi*ib;
        im[a] = ur*ia + ui*ra + vr*ib + vi*rb;
        re[b] = vpr*ra - vpi*ia + upr*rb - upi*ib;
        im[b] = vpr*ia + vpi*ra + upr*ib + upi*rb;
    }
}

__device__ __forceinline__ float4 zexp4_all(const float* re, const float* im) {
    float4 e = {0.f, 0.f, 0.f, 0.f};
    #pragma unroll
    for (int a = 0; a < 16; ++a) {
        float p = re[a]*re[a] + im[a]*im[a];
        e.x += (a & 1) ? -p : p;
        e.y += (a & 2) ? -p : p;
        e.z += (a & 4) ? -p : p;
        e.w += (a & 8) ? -p : p;
    }
    return e;
}

// ======================= kernel 0: gate-coefficient precompute =======================
// coef sets 0..23: [h][circ V/Q/K][wire] Rot coefs (8 floats each)
// sets 24..31: merge Rot coefs
// coef[256..263]: extra RX (c,s) for Q(h0),Q(h1),K(h0),K(h1)
__global__ __launch_bounds__(64)
void k_prep(const float* __restrict__ Vw, const float* __restrict__ Qw,
            const float* __restrict__ Kw, const float* __restrict__ Mw,
            float* __restrict__ coef)
{
    int tid = threadIdx.x;
    if (tid < 32) {
        float phi, th, om;
        if (tid < 24) {
            int h = tid / 12, cc = (tid % 12) / 4, w = tid % 4;
            const float* wp;
            if (cc == 0)      wp = Vw + h*12 + 3*w;
            else if (cc == 1) wp = Qw + h*13 + 3*w;
            else              wp = Kw + h*13 + 3*w;
            phi = wp[0]; th = wp[1]; om = wp[2];
        } else {
            int w = tid - 24;
            phi = Mw[3*w]; th = Mw[3*w+1]; om = Mw[3*w+2];
        }
        float st, ct, s1, c1, s2, c2;
        __sincosf(0.5f*th, &st, &ct);
        __sincosf(0.5f*(om+phi), &s1, &c1);
        __sincosf(0.5f*(om-phi), &s2, &c2);
        float* o = coef + tid*8;
        o[0] = c1*ct;  o[1] = -s1*ct;   // u  = ep*c,        ep = c1 - i s1
        o[2] = -c2*st; o[3] = s2*st;    // v  = -conj(em)*s, em = c2 + i s2
        o[4] = c2*st;  o[5] = s2*st;    // vp = em*s
        o[6] = c1*ct;  o[7] = s1*ct;    // up = conj(ep)*c
    } else if (tid < 36) {
        int k = tid - 32;               // 0,1: Q h0/h1 ; 2,3: K h0/h1
        int h = k & 1;
        float th = (k < 2 ? Qw : Kw)[h*13 + 12];
        float s, c; __sincosf(0.5f*th, &s, &c);
        coef[256 + k*2]     = c;
        coef[256 + k*2 + 1] = s;
    }
}

// ======================= kernel 1: LN + head circuits =======================
// thread per (token, head, circuit). blockIdx.y = hc : h = hc&1, c = hc>>1
// (c: 0=V, 1=Q, 2=K). Every wave is uniform in (h,c); the circuit body is the
// SAME code for all three circuits (runtime coef pointer) -> ~6x smaller
// kernel body (fits L1I) and 6x more waves (768 = 3/CU) vs round-1 version.
__global__ __launch_bounds__(64)
void k_heads(const float* __restrict__ x, const float* __restrict__ coef,
             float* __restrict__ Qo, float* __restrict__ Ko, float* __restrict__ Vo)
{
    int t = blockIdx.x * 64 + threadIdx.x;
    int hc = blockIdx.y;
    int h = hc & 1, c = hc >> 1;

    // ---- layernorm of this token's 8 features ----
    const float4* xp = (const float4*)(x + t*8);
    float4 xa = xp[0], xb = xp[1];
    float xv[8] = {xa.x, xa.y, xa.z, xa.w, xb.x, xb.y, xb.z, xb.w};
    float m = 0.f;
    #pragma unroll
    for (int e = 0; e < 8; ++e) m += xv[e];
    m *= 0.125f;
    float var = 0.f;
    #pragma unroll
    for (int e = 0; e < 8; ++e) { float d = xv[e]-m; var += d*d; }
    float inv = rsqrtf(var*0.125f + 1e-5f);

    // ---- angle encoding + CNOT ring on this head's 4 features ----
    float sr[16], si[16];
    #pragma unroll
    for (int a = 0; a < 16; ++a) { sr[a] = 0.f; si[a] = 0.f; }
    sr[0] = 1.f;
    float s, cc;
    __sincosf(0.5f*((xv[h*4+0]-m)*inv), &s, &cc); rx4<0>(sr, si, cc, s);
    __sincosf(0.5f*((xv[h*4+1]-m)*inv), &s, &cc); rx4<1>(sr, si, cc, s);
    __sincosf(0.5f*((xv[h*4+2]-m)*inv), &s, &cc); rx4<2>(sr, si, cc, s);
    __sincosf(0.5f*((xv[h*4+3]-m)*inv), &s, &cc); rx4<3>(sr, si, cc, s);
    cnot4<0,1>(sr, si); cnot4<1,2>(sr, si); cnot4<2,3>(sr, si); cnot4<3,0>(sr, si);

    // ---- trainable Rot layer (shared code, runtime coef pointer) ----
    const float* cfp = coef + (h*12 + c*4)*8;
    rot4<0>(sr, si, cfp + 0*8);
    rot4<1>(sr, si, cfp + 1*8);
    rot4<2>(sr, si, cfp + 2*8);
    rot4<3>(sr, si, cfp + 3*8);

    if (c != 0) {   // Q/K: extra RX on wire 0
        int k = (c - 1)*4 + h*2;
        rx4<0>(sr, si, coef[256 + k], coef[256 + k + 1]);
    }

    float4 e = zexp4_all(sr, si);
    if (c == 0)      ((float4*)Vo)[h*TOKS + t] = e;
    else if (c == 1) Qo[h*TOKS + t] = e.x;
    else             Ko[h*TOKS + t] = e.x;
}

// ======================= kernel 2: distance-kernel attention =======================
// grid 1024: blk = h*512 + b*32 + rg ; block 256 threads = 4 waves;
// each 16-lane group owns one output row i. Logits in [-2,0] -> no max needed.
__global__ __launch_bounds__(256)
void k_attn(const float* __restrict__ Qo, const float* __restrict__ Ko,
            const float* __restrict__ Vo, float* __restrict__ HO)
{
    __shared__ float Ks[512];
    __shared__ float4 Vs[512];
    int blk = blockIdx.x;
    int rg = blk & 31, b = (blk >> 5) & 15, h = blk >> 9;
    int base = h*TOKS + b*NS;
    int tid = threadIdx.x;
    #pragma unroll
    for (int k = 0; k < 2; ++k) {
        int j = k*256 + tid;
        Ks[j] = Ko[base + j];
        Vs[j] = ((const float4*)Vo)[base + j];
    }
    __syncthreads();

    int lane = tid & 63;
    int w = tid >> 6;          // wave 0..3
    int g = lane >> 4;         // 16-lane group 0..3
    int l16 = lane & 15;
    int i = rg*16 + w*4 + g;   // output row
    float q = Qo[base + i];

    float sum = 0.f, a0 = 0.f, a1 = 0.f, a2 = 0.f, a3 = 0.f;
    #pragma unroll
    for (int k = 0; k < 32; ++k) {
        int j = k*16 + l16;
        float d = q - Ks[j];
        float p = __expf(-0.5f*d*d);
        float4 vv = Vs[j];
        sum += p; a0 += p*vv.x; a1 += p*vv.y; a2 += p*vv.z; a3 += p*vv.w;
    }
    #pragma unroll
    for (int off = 1; off < 16; off <<= 1) {
        sum += __shfl_xor(sum, off, 16);
        a0  += __shfl_xor(a0,  off, 16);
        a1  += __shfl_xor(a1,  off, 16);
        a2  += __shfl_xor(a2,  off, 16);
        a3  += __shfl_xor(a3,  off, 16);
    }
    if (l16 == 0) {
        float r = 1.0f / sum;
        float4 o = {a0*r, a1*r, a2*r, a3*r};
        *((float4*)(HO + (b*NS + i)*8 + h*4)) = o;
    }
}

// ======================= kernel 3: n=8 merge circuit (wave per token) =======================
// amplitude a = (r<<6) | lane ; wire w <-> bit w of a (lane bits 0..5, reg bits 6..7)

template<int W>
__device__ __forceinline__ void c_rx(float (&sr)[4], float (&si)[4], float c, float s) {
    if constexpr (W <= 5) {
        #pragma unroll
        for (int r = 0; r < 4; ++r) {
            float pr = __shfl_xor(sr[r], 1 << W, 64);
            float pi = __shfl_xor(si[r], 1 << W, 64);
            float nr = c*sr[r] + s*pi;
            float ni = c*si[r] - s*pr;
            sr[r] = nr; si[r] = ni;
        }
    } else if constexpr (W == 6) {   // pairs (0,1),(2,3)
        #pragma unroll
        for (int k = 0; k < 2; ++k) {
            int lo = k*2, hi = lo + 1;
            float rl=sr[lo], il=si[lo], rh=sr[hi], ih=si[hi];
            sr[lo] = c*rl + s*ih; si[lo] = c*il - s*rh;
            sr[hi] = c*rh + s*il; si[hi] = c*ih - s*rl;
        }
    } else {                         // W==7: pairs (0,2),(1,3)
        #pragma unroll
        for (int k = 0; k < 2; ++k) {
            int lo = k, hi = k + 2;
            float rl=sr[lo], il=si[lo], rh=sr[hi], ih=si[hi];
            sr[lo] = c*rl + s*ih; si[lo] = c*il - s*rh;
            sr[hi] = c*rh + s*il; si[hi] = c*ih - s*rl;
        }
    }
}

template<int W>
__device__ __forceinline__ void c_rot(float (&sr)[4], float (&si)[4],
                                      const float* __restrict__ cf, int lane) {
    float ur=cf[0], ui=cf[1], vr=cf[2], vi=cf[3], vpr=cf[4], vpi=cf[5], upr=cf[6], upi=cf[7];
    if constexpr (W <= 5) {
        int bit = (lane >> W) & 1;
        float ar = bit ? upr : ur, ai = bit ? upi : ui;
        float br = bit ? vpr : vr, bi = bit ? vpi : vi;
        #pragma unroll
        for (int r = 0; r < 4; ++r) {
            float pr = __shfl_xor(sr[r], 1 << W, 64);
            float pi = __shfl_xor(si[r], 1 << W, 64);
            float nr = ar*sr[r] - ai*si[r] + br*pr - bi*pi;
            float ni = ar*si[r] + ai*sr[r] + br*pi + bi*pr;
            sr[r] = nr; si[r] = ni;
        }
    } else if constexpr (W == 6) {
        #pragma unroll
        for (int k = 0; k < 2; ++k) {
            int lo = k*2, hi = lo + 1;
            float rl=sr[lo], il=si[lo], rh=sr[hi], ih=si[hi];
            sr[lo] = ur*rl - ui*il + vr*rh - vi*ih;
            si[lo] = ur*il + ui*rl + vr*ih + vi*rh;
            sr[hi] = vpr*rl - vpi*il + upr*rh - upi*ih;
            si[hi] = vpr*il + vpi*rl + upr*ih + upi*rh;
        }
    } else {
        #pragma unroll
        for (int k = 0; k < 2; ++k) {
            int lo = k, hi = k + 2;
            float rl=sr[lo], il=si[lo], rh=sr[hi], ih=si[hi];
            sr[lo] = ur*rl - ui*il + vr*rh - vi*ih;
            si[lo] = ur*il + ui*rl + vr*ih + vi*rh;
            sr[hi] = vpr*rl - vpi*il + upr*rh - upi*ih;
            si[hi] = vpr*il + vpi*rl + upr*ih + upi*rh;
        }
    }
}

template<int C, int T>   // both lane bits, C control, T target
__device__ __forceinline__ void c_cnot_ll(float (&sr)[4], float (&si)[4], int lane) {
    int bc = (lane >> C) & 1;
    #pragma unroll
    for (int r = 0; r < 4; ++r) {
        float pr = __shfl_xor(sr[r], 1 << T, 64);
        float pi = __shfl_xor(si[r], 1 << T, 64);
        sr[r] = bc ? pr : sr[r];
        si[r] = bc ? pi : si[r];
    }
}

__global__ __launch_bounds__(256)
void k_merge(const float* __restrict__ HO, const float* __restrict__ x,
             const float* __restrict__ coef, float* __restrict__ out)
{
    int lane = threadIdx.x & 63;
    int t = blockIdx.x * 4 + (threadIdx.x >> 6);

    const float4* hp = (const float4*)(HO + t*8);
    float4 h0 = hp[0], h1 = hp[1];
    float ang[8] = {h0.x, h0.y, h0.z, h0.w, h1.x, h1.y, h1.z, h1.w};

    float sr[4], si[4];
    #pragma unroll
    for (int r = 0; r < 4; ++r) { sr[r] = 0.f; si[r] = 0.f; }
    sr[0] = (lane == 0) ? 1.f : 0.f;

    float s, c;
    // ---- angle encoding RX(ang[w]) on wire w ----
    __sincosf(0.5f*ang[0], &s, &c); c_rx<0>(sr, si, c, s);
    __sincosf(0.5f*ang[1], &s, &c); c_rx<1>(sr, si, c, s);
    __sincosf(0.5f*ang[2], &s, &c); c_rx<2>(sr, si, c, s);
    __sincosf(0.5f*ang[3], &s, &c); c_rx<3>(sr, si, c, s);
    __sincosf(0.5f*ang[4], &s, &c); c_rx<4>(sr, si, c, s);
    __sincosf(0.5f*ang[5], &s, &c); c_rx<5>(sr, si, c, s);
    __sincosf(0.5f*ang[6], &s, &c); c_rx<6>(sr, si, c, s);
    __sincosf(0.5f*ang[7], &s, &c); c_rx<7>(sr, si, c, s);

    // ---- CNOT ring (0,1)...(6,7),(7,0) ----
    c_cnot_ll<0,1>(sr, si, lane);
    c_cnot_ll<1,2>(sr, si, lane);
    c_cnot_ll<2,3>(sr, si, lane);
    c_cnot_ll<3,4>(sr, si, lane);
    c_cnot_ll<4,5>(sr, si, lane);
    { // (5,6): control lane bit5, target reg bit6: swap reg pairs (0,1),(2,3)
        int b5 = (lane >> 5) & 1;
        float t0=sr[0], t1=sr[1], t2=sr[2], t3=sr[3];
        sr[0] = b5 ? t1 : t0; sr[1] = b5 ? t0 : t1;
        sr[2] = b5 ? t3 : t2; sr[3] = b5 ? t2 : t3;
        float u0=si[0], u1=si[1], u2=si[2], u3=si[3];
        si[0] = b5 ? u1 : u0; si[1] = b5 ? u0 : u1;
        si[2] = b5 ? u3 : u2; si[3] = b5 ? u2 : u3;
    }
    { // (6,7): control reg bit6 (r=1,3), target reg bit7: swap r1<->r3
        float tr = sr[1]; sr[1] = sr[3]; sr[3] = tr;
        float ti = si[1]; si[1] = si[3]; si[3] = ti;
    }
    { // (7,0): control reg bit7 (r=2,3), target lane bit0
        sr[2] = __shfl_xor(sr[2], 1, 64); si[2] = __shfl_xor(si[2], 1, 64);
        sr[3] = __shfl_xor(sr[3], 1, 64); si[3] = __shfl_xor(si[3], 1, 64);
    }

    // ---- trainable Rot layer (precomputed coefs, sets 24..31) ----
    c_rot<0>(sr, si, coef + (24+0)*8, lane);
    c_rot<1>(sr, si, coef + (24+1)*8, lane);
    c_rot<2>(sr, si, coef + (24+2)*8, lane);
    c_rot<3>(sr, si, coef + (24+3)*8, lane);
    c_rot<4>(sr, si, coef + (24+4)*8, lane);
    c_rot<5>(sr, si, coef + (24+5)*8, lane);
    c_rot<6>(sr, si, coef + (24+6)*8, lane);
    c_rot<7>(sr, si, coef + (24+7)*8, lane);

    // ---- Z expectation on all 8 wires ----
    float p0 = sr[0]*sr[0] + si[0]*si[0];
    float p1 = sr[1]*sr[1] + si[1]*si[1];
    float p2 = sr[2]*sr[2] + si[2]*si[2];
    float p3 = sr[3]*sr[3] + si[3]*si[3];
    float P  = p0 + p1 + p2 + p3;
    float e0 = (lane & 1)  ? -P : P;
    float e1 = (lane & 2)  ? -P : P;
    float e2 = (lane & 4)  ? -P : P;
    float e3 = (lane & 8)  ? -P : P;
    float e4 = (lane & 16) ? -P : P;
    float e5 = (lane & 32) ? -P : P;
    float e6 = p0 - p1 + p2 - p3;
    float e7 = p0 + p1 - p2 - p3;
    #pragma unroll
    for (int off = 1; off < 64; off <<= 1) {
        e0 += __shfl_xor(e0, off, 64);
        e1 += __shfl_xor(e1, off, 64);
        e2 += __shfl_xor(e2, off, 64);
        e3 += __shfl_xor(e3, off, 64);
        e4 += __shfl_xor(e4, off, 64);
        e5 += __shfl_xor(e5, off, 64);
        e6 += __shfl_xor(e6, off, 64);
        e7 += __shfl_xor(e7, off, 64);
    }
    if (lane == 0) {
        const float4* xp = (const float4*)(x + t*8);
        float4 x0 = xp[0], x1 = xp[1];
        float4 o0 = {e0 + x0.x, e1 + x0.y, e2 + x0.z, e3 + x0.w};
        float4 o1 = {e4 + x1.x, e5 + x1.y, e6 + x1.z, e7 + x1.w};
        float4* op = (float4*)(out + t*8);
        op[0] = o0; op[1] = o1;
    }
}

// ======================= launch =======================
extern "C" void kernel_launch(void* const* d_in, const int* in_sizes, int n_in,
                              void* d_out, int out_size, void* d_ws, size_t ws_size,
                              hipStream_t stream) {
    (void)in_sizes; (void)n_in; (void)out_size; (void)ws_size;
    const float* x  = (const float*)d_in[0];
    const float* Vw = (const float*)d_in[1];
    const float* Qw = (const float*)d_in[2];
    const float* Kw = (const float*)d_in[3];
    const float* Mw = (const float*)d_in[4];
    float* out = (float*)d_out;
    float* ws  = (float*)d_ws;

    float* Qo   = ws + WS_Q;
    float* Ko   = ws + WS_K;
    float* Vo   = ws + WS_V;
    float* HO   = ws + WS_HO;
    float* coef = ws + WS_CF;

    hipLaunchKernelGGL(k_prep,  dim3(1),       dim3(64),  0, stream, Vw, Qw, Kw, Mw, coef);
    hipLaunchKernelGGL(k_heads, dim3(128, 6),  dim3(64),  0, stream, x, coef, Qo, Ko, Vo);
    hipLaunchKernelGGL(k_attn,  dim3(1024),    dim3(256), 0, stream, Qo, Ko, Vo, HO);
    hipLaunchKernelGGL(k_merge, dim3(2048),    dim3(256), 0, stream, HO, x, coef, out);
}

// Round 3
// 12.702 us; speedup vs baseline: 3.4315x; 2.7845x over previous
//
#include <hip/hip_runtime.h>

#define NS 512

// ============================================================================
// Closed-form collapse of the quantum circuits (derivation in journal):
//  - After RX-encoding, state is a product state; CNOT ring is a linear
//    bit-permutation; Rot layer folds into the measurement operator.
//  - All cross (X) terms vanish except on the last wire.
//  - V_w  = cos(th_w) * prefix-cos products ; V_3 gets one sin-product term.
//  - Q,K  = (cosb*costh0 + sinb*sinth0*sinom0) * cos g1 cos g2 cos g3.
//  - merge_w analogous on 8 wires with angles = attention output.
// ============================================================================

// ---- kernel 1: fused LN + closed-form QKV + distance-kernel attention ----
// grid 1024: blk = h*512 + b*32 + rg ; 256 threads = 4 waves;
// each 16-lane group owns one output row. Logits in [-2,0] -> no max needed.
__global__ __launch_bounds__(256)
void k_attn(const float* __restrict__ x, const float* __restrict__ Vw,
            const float* __restrict__ Qw, const float* __restrict__ Kw,
            float* __restrict__ HO)
{
    __shared__ float Qs[NS];
    __shared__ float Ks[NS];
    __shared__ float4 Vs[NS];

    int blk = blockIdx.x;
    int rg = blk & 31;
    int b  = (blk >> 5) & 15;
    int h  = blk >> 9;
    int tid = threadIdx.x;

    // ---- uniform weight-derived constants (scalar path, cheap) ----
    const float* qw = Qw + h*13;
    const float* kw = Kw + h*13;
    const float* vw = Vw + h*12;
    float sT, cT, sB, cB;
    __sincosf(qw[1], &sT, &cT); __sincosf(qw[12], &sB, &cB);
    float aQ = cB*cT + sB*sT*__sinf(qw[2]);
    __sincosf(kw[1], &sT, &cT); __sincosf(kw[12], &sB, &cB);
    float aK = cB*cT + sB*sT*__sinf(kw[2]);
    float vc0 = __cosf(vw[1]);
    float vc1 = __cosf(vw[4]);
    float vc2 = __cosf(vw[7]);
    float s3, vc3; __sincosf(vw[10], &s3, &vc3);
    float vs3 = s3 * __sinf(vw[9]);

    // ---- per-token closed-form Q,K,V (2 tokens per thread) ----
    #pragma unroll
    for (int k = 0; k < 2; ++k) {
        int tl = tid + k*256;
        const float4* xp = (const float4*)(x + (b*NS + tl)*8);
        float4 xa = xp[0], xb = xp[1];
        float xv[8] = {xa.x, xa.y, xa.z, xa.w, xb.x, xb.y, xb.z, xb.w};
        float m = 0.f;
        #pragma unroll
        for (int e = 0; e < 8; ++e) m += xv[e];
        m *= 0.125f;
        float var = 0.f;
        #pragma unroll
        for (int e = 0; e < 8; ++e) { float d = xv[e]-m; var += d*d; }
        float inv = rsqrtf(var*0.125f + 1e-5f);

        float cg[4], sg[4];
        #pragma unroll
        for (int i = 0; i < 4; ++i)
            __sincosf((xv[h*4+i]-m)*inv, &sg[i], &cg[i]);

        float c01  = cg[0]*cg[1];
        float c123 = cg[1]*cg[2]*cg[3];
        Qs[tl] = aQ * c123;
        Ks[tl] = aK * c123;
        float4 v;
        v.x = vc0 * c123;
        v.y = vc1 * c01;
        v.z = vc2 * c01 * cg[2];
        v.w = vc3 * c01 * cg[2] * cg[3] + vs3 * sg[0]*sg[1]*sg[3]*cg[2];
        Vs[tl] = v;
    }
    __syncthreads();

    // ---- attention: exp(-0.5*(Qi-Kj)^2), row-normalized ----
    int lane = tid & 63;
    int w = tid >> 6;          // wave 0..3
    int g = lane >> 4;         // 16-lane group 0..3
    int l16 = lane & 15;
    int i = rg*16 + w*4 + g;   // output row
    float q = Qs[i];

    float sum = 0.f, a0 = 0.f, a1 = 0.f, a2 = 0.f, a3 = 0.f;
    #pragma unroll
    for (int k = 0; k < 32; ++k) {
        int j = k*16 + l16;
        float d = q - Ks[j];
        float p = __expf(-0.5f*d*d);
        float4 vv = Vs[j];
        sum += p; a0 += p*vv.x; a1 += p*vv.y; a2 += p*vv.z; a3 += p*vv.w;
    }
    #pragma unroll
    for (int off = 1; off < 16; off <<= 1) {
        sum += __shfl_xor(sum, off, 16);
        a0  += __shfl_xor(a0,  off, 16);
        a1  += __shfl_xor(a1,  off, 16);
        a2  += __shfl_xor(a2,  off, 16);
        a3  += __shfl_xor(a3,  off, 16);
    }
    if (l16 == 0) {
        float r = 1.0f / sum;
        float4 o = {a0*r, a1*r, a2*r, a3*r};
        *((float4*)(HO + ((b*NS + i))*8 + h*4)) = o;
    }
}

// ---- kernel 2: closed-form 8-wire merge circuit + residual, thread/token ----
__global__ __launch_bounds__(64)
void k_merge(const float* __restrict__ HO, const float* __restrict__ x,
             const float* __restrict__ Mw, float* __restrict__ out)
{
    int t = blockIdx.x * 64 + threadIdx.x;

    // uniform weight constants
    float cT0 = __cosf(Mw[1]);
    float cT1 = __cosf(Mw[4]);
    float cT2 = __cosf(Mw[7]);
    float cT3 = __cosf(Mw[10]);
    float cT4 = __cosf(Mw[13]);
    float cT5 = __cosf(Mw[16]);
    float cT6 = __cosf(Mw[19]);
    float s7w, cT7; __sincosf(Mw[22], &s7w, &cT7);
    float vs77 = s7w * __sinf(Mw[21]);

    const float4* hp = (const float4*)(HO + t*8);
    float4 h0 = hp[0], h1 = hp[1];
    float a[8] = {h0.x, h0.y, h0.z, h0.w, h1.x, h1.y, h1.z, h1.w};

    float ca[8], sa0, sa1, sa7;
    __sincosf(a[0], &sa0, &ca[0]);
    __sincosf(a[1], &sa1, &ca[1]);
    ca[2] = __cosf(a[2]);
    ca[3] = __cosf(a[3]);
    ca[4] = __cosf(a[4]);
    ca[5] = __cosf(a[5]);
    ca[6] = __cosf(a[6]);
    __sincosf(a[7], &sa7, &ca[7]);

    float P1 = ca[0]*ca[1];
    float P2 = P1*ca[2];
    float P3 = P2*ca[3];
    float P4 = P3*ca[4];
    float P5 = P4*ca[5];
    float P6 = P5*ca[6];
    float P7 = P6*ca[7];
    float c34 = ca[3]*ca[4], c56 = ca[5]*ca[6];
    float Q17 = ca[1]*ca[2]*c34*c56*ca[7];   // cos a1..a7
    float M26 = ca[2]*c34*c56;               // cos a2..a6

    float e0 = cT0*Q17;
    float e1 = cT1*P1;
    float e2 = cT2*P2;
    float e3 = cT3*P3;
    float e4 = cT4*P4;
    float e5 = cT5*P5;
    float e6 = cT6*P6;
    float e7 = cT7*P7 + vs77 * sa0*sa1*sa7*M26;

    const float4* xp = (const float4*)(x + t*8);
    float4 x0 = xp[0], x1 = xp[1];
    float4 o0 = {e0 + x0.x, e1 + x0.y, e2 + x0.z, e3 + x0.w};
    float4 o1 = {e4 + x1.x, e5 + x1.y, e6 + x1.z, e7 + x1.w};
    float4* op = (float4*)(out + t*8);
    op[0] = o0; op[1] = o1;
}

// ======================= launch =======================
extern "C" void kernel_launch(void* const* d_in, const int* in_sizes, int n_in,
                              void* d_out, int out_size, void* d_ws, size_t ws_size,
                              hipStream_t stream) {
    (void)in_sizes; (void)n_in; (void)out_size; (void)ws_size;
    const float* x  = (const float*)d_in[0];
    const float* Vw = (const float*)d_in[1];
    const float* Qw = (const float*)d_in[2];
    const float* Kw = (const float*)d_in[3];
    const float* Mw = (const float*)d_in[4];
    float* out = (float*)d_out;
    float* HO  = (float*)d_ws;     // [8192][8]

    hipLaunchKernelGGL(k_attn,  dim3(1024), dim3(256), 0, stream, x, Vw, Qw, Kw, HO);
    hipLaunchKernelGGL(k_merge, dim3(128),  dim3(64),  0, stream, HO, x, Mw, out);
}

// Round 4
// 11.346 us; speedup vs baseline: 3.8417x; 1.1195x over previous
//
#include <hip/hip_runtime.h>

#define NS 512

// ============================================================================
// Fully-fused single kernel. Closed forms (verified R3, absmax 7.8e-3):
//   Q,K  = (cos b cos th0 + sin b sin th0 sin om0) * cos g1 cos g2 cos g3
//   V_w  = cos(th_w) * prefix-cos ; V_3 += sin th3 sin om3 * s0 s1 s3 c2
//   attention = row-softmax of exp(-0.5 (Qi-Kj)^2)   (logits in [-2,0])
//   merge_w analogous closed form on 8 wires; + residual.
// Block = (batch b, rowgroup rg of 16 rows). 256 threads.
//   P1: QKV (both heads, all 512 tokens of b) -> LDS
//   P2: 32 row-tasks (16 rows x 2 heads), 8 lanes each, 64 pairs/lane
//   P3: 16 threads: merge + residual -> out
// ============================================================================

__global__ __launch_bounds__(256)
void k_fused(const float* __restrict__ x, const float* __restrict__ Vw,
             const float* __restrict__ Qw, const float* __restrict__ Kw,
             const float* __restrict__ Mw, float* __restrict__ out)
{
    __shared__ float  Qs[2][NS];
    __shared__ float  Ks[2][NS];
    __shared__ float4 Vs[2][NS];
    __shared__ float  HOs[16][8];

    int tid = threadIdx.x;
    int b   = blockIdx.x >> 5;
    int rg  = blockIdx.x & 31;

    // ---- uniform weight-derived constants (all threads, branchless) ----
    float aQ[2], aK[2], vc0[2], vc1[2], vc2[2], vc3[2], vs3[2];
    #pragma unroll
    for (int h = 0; h < 2; ++h) {
        const float* qw = Qw + h*13;
        const float* kw = Kw + h*13;
        const float* vw = Vw + h*12;
        float sT, cT, sB, cB;
        __sincosf(qw[1], &sT, &cT); __sincosf(qw[12], &sB, &cB);
        aQ[h] = cB*cT + sB*sT*__sinf(qw[2]);
        __sincosf(kw[1], &sT, &cT); __sincosf(kw[12], &sB, &cB);
        aK[h] = cB*cT + sB*sT*__sinf(kw[2]);
        vc0[h] = __cosf(vw[1]);
        vc1[h] = __cosf(vw[4]);
        vc2[h] = __cosf(vw[7]);
        float s3; __sincosf(vw[10], &s3, &vc3[h]);
        vs3[h] = s3 * __sinf(vw[9]);
    }

    // ---- phase 1: closed-form QKV for 2 tokens/thread, both heads ----
    #pragma unroll
    for (int k = 0; k < 2; ++k) {
        int tl = tid + k*256;
        const float4* xp = (const float4*)(x + (b*NS + tl)*8);
        float4 xa = xp[0], xb = xp[1];
        float xv[8] = {xa.x, xa.y, xa.z, xa.w, xb.x, xb.y, xb.z, xb.w};
        float m = 0.f;
        #pragma unroll
        for (int e = 0; e < 8; ++e) m += xv[e];
        m *= 0.125f;
        float var = 0.f;
        #pragma unroll
        for (int e = 0; e < 8; ++e) { float d = xv[e]-m; var += d*d; }
        float inv = rsqrtf(var*0.125f + 1e-5f);

        #pragma unroll
        for (int h = 0; h < 2; ++h) {
            float cg[4], sg[4];
            #pragma unroll
            for (int i = 0; i < 4; ++i)
                __sincosf((xv[h*4+i]-m)*inv, &sg[i], &cg[i]);
            float c01  = cg[0]*cg[1];
            float c123 = cg[1]*cg[2]*cg[3];
            Qs[h][tl] = aQ[h] * c123;
            Ks[h][tl] = aK[h] * c123;
            float4 v;
            v.x = vc0[h] * c123;
            v.y = vc1[h] * c01;
            v.z = vc2[h] * c01 * cg[2];
            v.w = vc3[h] * c01 * cg[2] * cg[3] + vs3[h] * sg[0]*sg[1]*sg[3]*cg[2];
            Vs[h][tl] = v;
        }
    }
    __syncthreads();

    // ---- phase 2: attention, 8 lanes per (row,head) task ----
    {
        int lane = tid & 63;
        int w    = tid >> 6;
        int task = w*8 + (lane >> 3);   // 0..31
        int l8   = lane & 7;
        int hh   = task >> 4;
        int r    = task & 15;           // row within group
        int row  = rg*16 + r;
        float q  = Qs[hh][row];

        float sum = 0.f, a0 = 0.f, a1 = 0.f, a2 = 0.f, a3 = 0.f;
        #pragma unroll 8
        for (int k = 0; k < 64; ++k) {
            int j = k*8 + l8;
            float d = q - Ks[hh][j];
            float p = __expf(-0.5f*d*d);
            float4 vv = Vs[hh][j];
            sum += p; a0 += p*vv.x; a1 += p*vv.y; a2 += p*vv.z; a3 += p*vv.w;
        }
        #pragma unroll
        for (int off = 1; off < 8; off <<= 1) {
            sum += __shfl_xor(sum, off, 8);
            a0  += __shfl_xor(a0,  off, 8);
            a1  += __shfl_xor(a1,  off, 8);
            a2  += __shfl_xor(a2,  off, 8);
            a3  += __shfl_xor(a3,  off, 8);
        }
        if (l8 == 0) {
            float rr = 1.0f / sum;
            HOs[r][hh*4 + 0] = a0*rr;
            HOs[r][hh*4 + 1] = a1*rr;
            HOs[r][hh*4 + 2] = a2*rr;
            HOs[r][hh*4 + 3] = a3*rr;
        }
    }
    __syncthreads();

    // ---- phase 3: merge closed form + residual, 16 threads ----
    if (tid < 16) {
        float cT0 = __cosf(Mw[1]);
        float cT1 = __cosf(Mw[4]);
        float cT2 = __cosf(Mw[7]);
        float cT3 = __cosf(Mw[10]);
        float cT4 = __cosf(Mw[13]);
        float cT5 = __cosf(Mw[16]);
        float cT6 = __cosf(Mw[19]);
        float s7w, cT7; __sincosf(Mw[22], &s7w, &cT7);
        float vs77 = s7w * __sinf(Mw[21]);

        int t = b*NS + rg*16 + tid;
        float a[8];
        #pragma unroll
        for (int e = 0; e < 8; ++e) a[e] = HOs[tid][e];

        float ca[8], sa0, sa1, sa7;
        __sincosf(a[0], &sa0, &ca[0]);
        __sincosf(a[1], &sa1, &ca[1]);
        ca[2] = __cosf(a[2]);
        ca[3] = __cosf(a[3]);
        ca[4] = __cosf(a[4]);
        ca[5] = __cosf(a[5]);
        ca[6] = __cosf(a[6]);
        __sincosf(a[7], &sa7, &ca[7]);

        float P1 = ca[0]*ca[1];
        float P2 = P1*ca[2];
        float P3 = P2*ca[3];
        float P4 = P3*ca[4];
        float P5 = P4*ca[5];
        float P6 = P5*ca[6];
        float P7 = P6*ca[7];
        float c34 = ca[3]*ca[4], c56 = ca[5]*ca[6];
        float Q17 = ca[1]*ca[2]*c34*c56*ca[7];
        float M26 = ca[2]*c34*c56;

        const float4* xp = (const float4*)(x + t*8);
        float4 x0 = xp[0], x1 = xp[1];
        float4 o0 = {cT0*Q17 + x0.x, cT1*P1 + x0.y, cT2*P2 + x0.z, cT3*P3 + x0.w};
        float4 o1 = {cT4*P4 + x1.x, cT5*P5 + x1.y, cT6*P6 + x1.z,
                     cT7*P7 + vs77*sa0*sa1*sa7*M26 + x1.w};
        float4* op = (float4*)(out + t*8);
        op[0] = o0; op[1] = o1;
    }
}

// ======================= launch =======================
extern "C" void kernel_launch(void* const* d_in, const int* in_sizes, int n_in,
                              void* d_out, int out_size, void* d_ws, size_t ws_size,
                              hipStream_t stream) {
    (void)in_sizes; (void)n_in; (void)out_size; (void)d_ws; (void)ws_size;
    const float* x  = (const float*)d_in[0];
    const float* Vw = (const float*)d_in[1];
    const float* Qw = (const float*)d_in[2];
    const float* Kw = (const float*)d_in[3];
    const float* Mw = (const float*)d_in[4];
    float* out = (float*)d_out;

    hipLaunchKernelGGL(k_fused, dim3(512), dim3(256), 0, stream,
                       x, Vw, Qw, Kw, Mw, out);
}